// Round 13
// baseline (456.594 us; speedup 1.0000x reference)
//
#include <hip/hip_runtime.h>
#include <hip/hip_bf16.h>

#define N_NODES_DIM0 128

typedef unsigned short u16;
typedef unsigned int u32;
typedef __attribute__((ext_vector_type(8))) short short8;
typedef __attribute__((ext_vector_type(4))) float f32x4;

__device__ __forceinline__ float bf2f(u16 h) { return __uint_as_float((u32)h << 16); }
__device__ __forceinline__ u16 f2bf(float f) {
    u32 u = __float_as_uint(f);
    u32 r = (u + 0x7FFFu + ((u >> 16) & 1u)) >> 16;  // round-to-nearest-even
    return (u16)r;
}

// async global->LDS, 16 B per lane; lds dest = wave-uniform base + lane*16
__device__ __forceinline__ void gl2lds16(const u16* g, u16* lds_base) {
    __builtin_amdgcn_global_load_lds(
        (const __attribute__((address_space(1))) u32*)g,
        (__attribute__((address_space(3))) u32*)lds_base, 16, 0, 0);
}

// ---------------- CSR build (scan-free: wave-scan + atomic bump allocator) ----------------

__global__ void zero_int_kernel(int* p, int n) {
    int i = blockIdx.x * blockDim.x + threadIdx.x;
    if (i < n) p[i] = 0;
}

__global__ void hist_kernel(const int* __restrict__ dst, int* __restrict__ cnt, int e) {
    int i = blockIdx.x * blockDim.x + threadIdx.x;
    if (i < e) atomicAdd(&cnt[dst[i]], 1);
}

// row_start[i] = segment base (segments in arbitrary order); dinv[i] = rsqrt(deg+1).
__global__ void alloc_kernel(const int* __restrict__ cnt, int* __restrict__ row_start,
                             float* __restrict__ dinv, int* __restrict__ cursor, int n) {
    int i = blockIdx.x * blockDim.x + threadIdx.x;
    int lane = threadIdx.x & 63;
    int v = (i < n) ? cnt[i] : 0;
    int s = v;  // inclusive wave prefix
#pragma unroll
    for (int off = 1; off < 64; off <<= 1) {
        int x = __shfl_up(s, off, 64);
        if (lane >= off) s += x;
    }
    int total = __shfl(s, 63, 64);
    int base = 0;
    if (lane == 0) base = atomicAdd(cursor, total);
    base = __shfl(base, 0, 64);
    if (i < n) {
        row_start[i] = base + s - v;  // exclusive within wave
        dinv[i] = rsqrtf((float)v + 1.0f);
    }
}

// bump-fill: after completion row_start[d] == segment end (beg = end - cnt[d])
__global__ void fill_kernel(const int* __restrict__ src, const int* __restrict__ dst,
                            int* __restrict__ row_start, int* __restrict__ csr_src, int e) {
    int i = blockIdx.x * blockDim.x + threadIdx.x;
    if (i < e) {
        int d = dst[i];
        int pos = atomicAdd(&row_start[d], 1);
        csr_src[pos] = src[i];
    }
}

// ---------------- merged: LDS-tiled weight transpose-cast + input scale-cast ----------------
__global__ __launch_bounds__(256) void prep_kernel(
    const float* __restrict__ W0, const float* __restrict__ W1,
    const float* __restrict__ W2, const float* __restrict__ W3, u16* __restrict__ Wt,
    const float* __restrict__ x, const float* __restrict__ dinv,
    u16* __restrict__ Y, int N) {
    int bid = blockIdx.x;
    if (bid < 784) {
        __shared__ float tile[32][33];
        const float* W; u16* out; int K, F, kb, nb;
        if (bid < 128)      { W = W0; out = Wt;          K = 128;  F = 1024; kb = bid & 3;  nb = bid >> 2; }
        else if (bid < 640) { int l = bid - 128; W = W1; out = Wt + 131072; K = 1024; F = 512; kb = l & 31; nb = l >> 5; }
        else if (bid < 768) { int l = bid - 640; W = W2; out = Wt + 655360; K = 512;  F = 256; kb = l & 15; nb = l >> 4; }
        else                { int l = bid - 768; W = W3; out = Wt + 786432; K = 256;  F = 64;  kb = l & 7;  nb = l >> 3; }
        int k0 = kb * 32, n0 = nb * 32;
        int tx = threadIdx.x & 31, ty = threadIdx.x >> 5;
#pragma unroll
        for (int i = 0; i < 4; ++i) {
            int k = ty + i * 8;
            tile[k][tx] = W[(size_t)(k0 + k) * F + n0 + tx];  // coalesced 128B rows
        }
        __syncthreads();
#pragma unroll
        for (int i = 0; i < 4; ++i) {
            int n = ty + i * 8;
            out[(size_t)(n0 + n) * K + k0 + tx] = f2bf(tile[tx][n]);  // coalesced bf16 rows
        }
    } else {
        int gid = (bid - 784) * 256 + threadIdx.x;
        int node = gid >> 5;
        int c4 = (gid & 31) * 4;
        if (node >= N) return;
        float dv = dinv[node];
        float4 v = *reinterpret_cast<const float4*>(x + (size_t)node * 128 + c4);
        ushort4 r;
        r.x = f2bf(dv * v.x); r.y = f2bf(dv * v.y);
        r.z = f2bf(dv * v.z); r.w = f2bf(dv * v.w);
        *reinterpret_cast<ushort4*>(Y + (size_t)node * 128 + c4) = r;
    }
}

// ---------------- helpers: bf16x8 accumulate ----------------
__device__ __forceinline__ void add8(float* acc, const u16* p) {
    short8 v = *reinterpret_cast<const short8*>(p);
#pragma unroll
    for (int w = 0; w < 8; ++w) acc[w] += bf2f((u16)v[w]);
}
__device__ __forceinline__ void add8v(float* acc, short8 v) {
#pragma unroll
    for (int w = 0; w < 8; ++w) acc[w] += bf2f((u16)v[w]);
}

// generic CSR gather-accumulate with 8/4/1 unroll ladder (latency-bound gathers:
// 8 independent 16B loads in flight per lane doubles concurrency vs unroll-4)
__device__ __forceinline__ void gather_sum(float* acc, const u16* __restrict__ base,
                                           const int* __restrict__ csr_src,
                                           int beg, int end, int stride, int ch) {
    int e = beg;
    for (; e + 8 <= end; e += 8) {
        short8 v0 = *reinterpret_cast<const short8*>(base + (size_t)csr_src[e]     * stride + ch);
        short8 v1 = *reinterpret_cast<const short8*>(base + (size_t)csr_src[e + 1] * stride + ch);
        short8 v2 = *reinterpret_cast<const short8*>(base + (size_t)csr_src[e + 2] * stride + ch);
        short8 v3 = *reinterpret_cast<const short8*>(base + (size_t)csr_src[e + 3] * stride + ch);
        short8 v4 = *reinterpret_cast<const short8*>(base + (size_t)csr_src[e + 4] * stride + ch);
        short8 v5 = *reinterpret_cast<const short8*>(base + (size_t)csr_src[e + 5] * stride + ch);
        short8 v6 = *reinterpret_cast<const short8*>(base + (size_t)csr_src[e + 6] * stride + ch);
        short8 v7 = *reinterpret_cast<const short8*>(base + (size_t)csr_src[e + 7] * stride + ch);
        add8v(acc, v0); add8v(acc, v1); add8v(acc, v2); add8v(acc, v3);
        add8v(acc, v4); add8v(acc, v5); add8v(acc, v6); add8v(acc, v7);
    }
    for (; e + 4 <= end; e += 4) {
        short8 v0 = *reinterpret_cast<const short8*>(base + (size_t)csr_src[e]     * stride + ch);
        short8 v1 = *reinterpret_cast<const short8*>(base + (size_t)csr_src[e + 1] * stride + ch);
        short8 v2 = *reinterpret_cast<const short8*>(base + (size_t)csr_src[e + 2] * stride + ch);
        short8 v3 = *reinterpret_cast<const short8*>(base + (size_t)csr_src[e + 3] * stride + ch);
        add8v(acc, v0); add8v(acc, v1); add8v(acc, v2); add8v(acc, v3);
    }
    for (; e < end; ++e) add8(acc, base + (size_t)csr_src[e] * stride + ch);
}

// ---------------- layer-1 pre-aggregation: Z[d] = bf16(dinv[d]*(Y[d]+sum Y[src])) ----------------
__global__ void agg_pre_kernel(const int* __restrict__ row_end, const int* __restrict__ cnt,
                               const int* __restrict__ csr_src,
                               const u16* __restrict__ Y, const float* __restrict__ dinv,
                               u16* __restrict__ Z, int N) {
    int gid = blockIdx.x * blockDim.x + threadIdx.x;
    int node = gid >> 4;          // 16 threads/node
    int ch = (gid & 15) * 8;      // 8 cols each
    if (node >= N) return;
    float acc[8] = {};
    add8(acc, Y + (size_t)node * 128 + ch);  // self-loop
    int end = row_end[node], beg = end - cnt[node];
    gather_sum(acc, Y, csr_src, beg, end, 128, ch);
    float dv = dinv[node];
    short8 r;
#pragma unroll
    for (int w = 0; w < 8; ++w) r[w] = (short)f2bf(dv * acc[w]);
    *reinterpret_cast<short8*>(Z + (size_t)node * 128 + ch) = r;
}

// ---------------- MFMA bf16 GEMM (R10 form: pointer-bump staging, normal stores) -----------
// Out[N,F] from X[N,K] bf16 and Wt[F,K] bf16.
// EPI=0: Out = bf16(dinv[row] * acc)       EPI=1: Out = bf16(relu(acc + bias[col]))
// BM=128, BK=64, 256 threads = 4 waves (2x2), wave tile 64 x (BN/2).
// R11 lesson: BM=256's 128-acc tile crosses the 256-reg cliff (1 wave/SIMD, 1.8x slower).
// R12 lesson: u32-offset staging and non-temporal epilogue stores both regress; the
// 64-bit pointer-bump + normal-store form below is the measured optimum (~80 us @ L2 layer).
// LDS: slot c (16B) holds global chunk (r=c>>3, q=(c^r)&7); XOR swizzle keeps
// fragment ds_read_b128 conflict-free with linear wave-uniform gl2lds dest.
template <int BN, int EPI>
__global__ __launch_bounds__(256) void gemm_mfma_kernel(
    const u16* __restrict__ X, const u16* __restrict__ Wt,
    const float* __restrict__ dinv, const float* __restrict__ bias,
    u16* __restrict__ Out, int N, int K, int F, int lgnx) {
    constexpr int BM = 128, BK = 64;
    constexpr int RA = (BM * 8) / 256;  // 4 staging rounds for A
    constexpr int RB = (BN * 8) / 256;  // 4 (BN=128) or 2 (BN=64)
    __shared__ u16 As[BM * BK];   // 16 KB
    __shared__ u16 Bs[BN * BK];   // 16 KB / 8 KB

    const int t = threadIdx.x;
    const int wave = t >> 6;
    const int lane = t & 63;
    const int m16 = lane & 15;
    const int quad = lane >> 4;

    // XCD-aware decode
    const int id = blockIdx.x;
    const int wi = id & ((8 << lgnx) - 1);
    const int g  = id >> (3 + lgnx);
    const int rb = g * 8 + (wi & 7);
    const int cb = wi >> 3;
    const int row0 = rb * BM;
    const int col0 = cb * BN;
    if (row0 >= N) return;

    constexpr int WN = BN / 2;
    constexpr int NI = 4;
    constexpr int NJ = WN / 16;
    const int wm = (wave >> 1) * 64;
    const int wn = (wave & 1) * WN;

    // ---- precompute staging pointers (global src advances by BK per iter) ----
    const u16* aSrc[RA];
    u16* aDst[RA];
#pragma unroll
    for (int rr = 0; rr < RA; ++rr) {
        int c = rr * 256 + t;
        int r = c >> 3;
        int q = (c ^ r) & 7;  // XOR swizzle
        int grow = row0 + r;
        if (grow >= N) grow = 0;  // clamped rows feed only epilogue-guarded outputs
        aSrc[rr] = X + (size_t)grow * K + q * 8;
        aDst[rr] = &As[(size_t)(rr * 256 + wave * 64) * 8];
    }
    const u16* bSrc[RB];
    u16* bDst[RB];
#pragma unroll
    for (int rr = 0; rr < RB; ++rr) {
        int c = rr * 256 + t;
        int r = c >> 3;
        int q = (c ^ r) & 7;
        bSrc[rr] = Wt + (size_t)(col0 + r) * K + q * 8;
        bDst[rr] = &Bs[(size_t)(rr * 256 + wave * 64) * 8];
    }

    // ---- fragment LDS byte offsets (u32, loop-invariant) ----
    u32 aOff[NI][2], bOff[NJ][2];
#pragma unroll
    for (int i = 0; i < NI; ++i)
#pragma unroll
        for (int h = 0; h < 2; ++h) {
            int row = wm + i * 16 + m16;
            int qg = h * 4 + quad;
            aOff[i][h] = (u32)(((row << 3) | ((qg ^ row) & 7)) * 16);
        }
#pragma unroll
    for (int j = 0; j < NJ; ++j)
#pragma unroll
        for (int h = 0; h < 2; ++h) {
            int row = wn + j * 16 + m16;
            int qg = h * 4 + quad;
            bOff[j][h] = (u32)(((row << 3) | ((qg ^ row) & 7)) * 16);
        }
    const char* AsB = reinterpret_cast<const char*>(As);
    const char* BsB = reinterpret_cast<const char*>(Bs);

    f32x4 acc[NI][NJ] = {};

    for (int k0 = 0; k0 < K; k0 += BK) {
#pragma unroll
        for (int rr = 0; rr < RA; ++rr) {
            gl2lds16(aSrc[rr], aDst[rr]);
            aSrc[rr] += BK;
        }
#pragma unroll
        for (int rr = 0; rr < RB; ++rr) {
            gl2lds16(bSrc[rr], bDst[rr]);
            bSrc[rr] += BK;
        }
        __syncthreads();  // drains vmcnt -> LDS valid

#pragma unroll
        for (int h = 0; h < 2; ++h) {  // two 16x16x32 k-slices per BK=64
            short8 af[NI], bf[NJ];
#pragma unroll
            for (int i = 0; i < NI; ++i)
                af[i] = *reinterpret_cast<const short8*>(AsB + aOff[i][h]);
#pragma unroll
            for (int j = 0; j < NJ; ++j)
                bf[j] = *reinterpret_cast<const short8*>(BsB + bOff[j][h]);
#pragma unroll
            for (int i = 0; i < NI; ++i)
#pragma unroll
                for (int j = 0; j < NJ; ++j)
                    acc[i][j] = __builtin_amdgcn_mfma_f32_16x16x32_bf16(af[i], bf[j], acc[i][j], 0, 0, 0);
        }
        __syncthreads();
    }

    // epilogue: C/D layout col=lane&15, row=quad*4+reg  [measured m89/m91]
#pragma unroll
    for (int i = 0; i < NI; ++i) {
#pragma unroll
        for (int r = 0; r < 4; ++r) {
            int grow = row0 + wm + i * 16 + quad * 4 + r;
            if (grow >= N) continue;
            float dv = (EPI == 0) ? dinv[grow] : 0.f;
#pragma unroll
            for (int j = 0; j < NJ; ++j) {
                int gcol = col0 + wn + j * 16 + m16;
                float v = acc[i][j][r];
                if (EPI == 0) v = dv * v;
                else          v = fmaxf(v + bias[gcol], 0.f);
                Out[(size_t)grow * F + gcol] = f2bf(v);
            }
        }
    }
}

// ---------------- post-aggregation: X_next = bf16(relu(dinv*(G[d]+sum G[src]) + b)) ----------------
__global__ void agg_post_kernel(const int* __restrict__ row_end, const int* __restrict__ cnt,
                                const int* __restrict__ csr_src,
                                const u16* __restrict__ Gc, const float* __restrict__ dinv,
                                const float* __restrict__ bias, u16* __restrict__ XO,
                                int N, int F, int lgG) {
    int gid = blockIdx.x * blockDim.x + threadIdx.x;
    int node = gid >> lgG;
    int ch = (gid & ((1 << lgG) - 1)) * 8;
    if (node >= N) return;
    float acc[8] = {};
    add8(acc, Gc + (size_t)node * F + ch);  // self-loop
    int end = row_end[node], beg = end - cnt[node];
    gather_sum(acc, Gc, csr_src, beg, end, F, ch);
    float dv = dinv[node];
    short8 r;
#pragma unroll
    for (int w = 0; w < 8; ++w)
        r[w] = (short)f2bf(fmaxf(fmaf(dv, acc[w], bias[ch + w]), 0.f));
    *reinterpret_cast<short8*>(XO + (size_t)node * F + ch) = r;
}

// ---------------- layer 5 (F_out = 1), bf16 input ----------------
__global__ void layer5_dot_kernel(const u16* __restrict__ X, const float* __restrict__ W5,
                                  const float* __restrict__ dinv, float* __restrict__ g5, int N) {
    int gtid = blockIdx.x * blockDim.x + threadIdx.x;
    int node = gtid >> 6;
    int lane = threadIdx.x & 63;
    if (node >= N) return;
    float v = bf2f(X[(size_t)node * 64 + lane]) * W5[lane];
#pragma unroll
    for (int off = 32; off > 0; off >>= 1) v += __shfl_down(v, off, 64);
    if (lane == 0) g5[node] = dinv[node] * v;
}

__global__ void agg5_kernel(const int* __restrict__ row_end, const int* __restrict__ cnt,
                            const int* __restrict__ csr_src,
                            const float* __restrict__ g5, const float* __restrict__ dinv,
                            const float* __restrict__ b5, float* __restrict__ out, int N) {
    int i = blockIdx.x * blockDim.x + threadIdx.x;
    if (i >= N) return;
    float acc = g5[i];
    int end = row_end[i], e = end - cnt[i];
    for (; e + 4 <= end; e += 4) {
        float a = g5[csr_src[e]];
        float b = g5[csr_src[e + 1]];
        float c = g5[csr_src[e + 2]];
        float d = g5[csr_src[e + 3]];
        acc += (a + b) + (c + d);
    }
    for (; e < end; ++e) acc += g5[csr_src[e]];
    out[i] = fmaxf(fmaf(dinv[i], acc, b5[0]), 0.f);
}

// ---------------- launch ----------------

static inline size_t align_up(size_t x) { return (x + 255) & ~(size_t)255; }
static inline int round_up8(int x) { return (x + 7) & ~7; }

extern "C" void kernel_launch(void* const* d_in, const int* in_sizes, int n_in,
                              void* d_out, int out_size, void* d_ws, size_t ws_size,
                              hipStream_t stream) {
    const float* x  = (const float*)d_in[0];
    const int*   ei = (const int*)d_in[1];
    const int E = in_sizes[1] / 2;
    const int N = in_sizes[0] / N_NODES_DIM0;
    const int* src = ei;
    const int* dst = ei + E;

    const float* W[5] = {(const float*)d_in[2], (const float*)d_in[4], (const float*)d_in[6],
                         (const float*)d_in[8], (const float*)d_in[10]};
    const float* B[5] = {(const float*)d_in[3], (const float*)d_in[5], (const float*)d_in[7],
                         (const float*)d_in[9], (const float*)d_in[11]};

    const int Ks[4] = {128, 1024, 512, 256};
    const int Fs[4] = {1024, 512, 256, 64};

    // workspace carve — peak ~209 MB
    char* w = (char*)d_ws;
    size_t off = 0;
    float* dinv    = (float*)(w + off); off += align_up((size_t)N * 4);
    float* g5      = (float*)(w + off); off += align_up((size_t)N * 4);
    int*   cnt     = (int*)(w + off);   off += align_up((size_t)(N + 1) * 4);  // cnt[N] = cursor
    int*   rstart  = (int*)(w + off);   off += align_up((size_t)N * 4);        // bump ptr -> row end
    int*   csr_src = (int*)(w + off);   off += align_up((size_t)E * 4);        // 1.6 MB
    // Wt: contiguous, all 4 layers (sizes are 256-multiples -> no gaps)
    u16* WtBase = (u16*)(w + off);
    u16* Wt[4];
    {
        size_t cum = 0;
        for (int l = 0; l < 4; ++l) {
            Wt[l] = WtBase + cum;
            cum += (size_t)Ks[l] * Fs[l];
        }
        off += align_up(cum * 2);
    }
    // Gc region (51.2 MB) also hosts Y+Z (12.8+12.8 MB), used only before layer-2 GEMM
    char* REG = w + off;               off += align_up((size_t)N * 512 * 2);    // 51.2 MB
    u16* Y  = (u16*)REG;
    u16* Z  = (u16*)(REG + align_up((size_t)N * 128 * 2));
    u16* Gc = (u16*)REG;
    u16* XA = (u16*)(w + off);         off += align_up((size_t)N * 1024 * 2);   // 102.4 MB
    u16* XB = (u16*)(w + off);         off += align_up((size_t)N * 512 * 2);    // 51.2 MB
    (void)ws_size;

    // ---- CSR build (scan-free) ----
    zero_int_kernel<<<(N + 1 + 255) / 256, 256, 0, stream>>>(cnt, N + 1);
    hist_kernel<<<(E + 255) / 256, 256, 0, stream>>>(dst, cnt, E);
    alloc_kernel<<<(N + 255) / 256, 256, 0, stream>>>(cnt, rstart, dinv, &cnt[N], N);
    fill_kernel<<<(E + 255) / 256, 256, 0, stream>>>(src, dst, rstart, csr_src, E);
    // after fill: rstart[i] == segment end; beg = rstart[i] - cnt[i]

    // ---- weights transpose-cast + input scale-cast, single merged launch ----
    {
        int scale_blocks = (N * 32 + 255) / 256;
        prep_kernel<<<784 + scale_blocks, 256, 0, stream>>>(
            W[0], W[1], W[2], W[3], WtBase, x, dinv, Y, N);
    }

    const int ny = (N + 127) / 128;
    const int ny8 = round_up8(ny);

    // ---- layer 1: aggregate-first (K=128 < F=1024) ----
    agg_pre_kernel<<<(N * 16 + 255) / 256, 256, 0, stream>>>(rstart, cnt, csr_src, Y, dinv, Z, N);
    {
        // F=1024, BN=128 -> nx=8, lgnx=3
        gemm_mfma_kernel<128, 1><<<ny8 * 8, 256, 0, stream>>>(Z, Wt[0], dinv, B[0], XA,
                                                              N, 128, 1024, 3);
    }

    // ---- layers 2..4: GEMM (dinv epilogue) -> aggregate (bias+relu) ----
    u16* Xin[3]  = {XA, XB, XA};
    u16* Xout[3] = {XB, XA, XB};
    for (int l = 1; l < 4; ++l) {
        const int K = Ks[l], F = Fs[l];
        if (F >= 128) {
            int nx = F / 128;
            int lgnx = (nx == 4) ? 2 : (nx == 2) ? 1 : 0;
            gemm_mfma_kernel<128, 0><<<ny8 * nx, 256, 0, stream>>>(
                Xin[l - 1], Wt[l], dinv, B[l], Gc, N, K, F, lgnx);
        } else {
            // F=64, BN=64 -> nx=1, lgnx=0
            gemm_mfma_kernel<64, 0><<<ny8, 256, 0, stream>>>(
                Xin[l - 1], Wt[l], dinv, B[l], Gc, N, K, F, 0);
        }
        int lgG = (F == 512) ? 6 : (F == 256) ? 5 : 3;  // F/8 threads per node
        long long tot = (long long)N << lgG;
        agg_post_kernel<<<(unsigned)((tot + 255) / 256), 256, 0, stream>>>(
            rstart, cnt, csr_src, Gc, dinv, B[l], Xout[l - 1], N, F, lgG);
    }

    // ---- layer 5: [N,64](bf16) @ [64,1] ----
    layer5_dot_kernel<<<(N * 64 + 255) / 256, 256, 0, stream>>>(XB, W[4], dinv, g5, N);
    agg5_kernel<<<(N + 255) / 256, 256, 0, stream>>>(rstart, cnt, csr_src, g5, dinv, B[4],
                                                     (float*)d_out, N);
}

// Round 14
// 438.705 us; speedup vs baseline: 1.0408x; 1.0408x over previous
//
#include <hip/hip_runtime.h>
#include <hip/hip_bf16.h>

#define N_NODES_DIM0 128

typedef unsigned short u16;
typedef unsigned int u32;
typedef __attribute__((ext_vector_type(8))) short short8;
typedef __attribute__((ext_vector_type(4))) float f32x4;

__device__ __forceinline__ float bf2f(u16 h) { return __uint_as_float((u32)h << 16); }
__device__ __forceinline__ u16 f2bf(float f) {
    u32 u = __float_as_uint(f);
    u32 r = (u + 0x7FFFu + ((u >> 16) & 1u)) >> 16;  // round-to-nearest-even
    return (u16)r;
}

// async global->LDS, 16 B per lane; lds dest = wave-uniform base + lane*16
__device__ __forceinline__ void gl2lds16(const u16* g, u16* lds_base) {
    __builtin_amdgcn_global_load_lds(
        (const __attribute__((address_space(1))) u32*)g,
        (__attribute__((address_space(3))) u32*)lds_base, 16, 0, 0);
}

// ---------------- CSR build (scan-free: wave-scan + atomic bump allocator) ----------------

__global__ void zero_int_kernel(int* p, int n) {
    int i = blockIdx.x * blockDim.x + threadIdx.x;
    if (i < n) p[i] = 0;
}

__global__ void hist_kernel(const int* __restrict__ dst, int* __restrict__ cnt, int e) {
    int i = blockIdx.x * blockDim.x + threadIdx.x;
    if (i < e) atomicAdd(&cnt[dst[i]], 1);
}

// row_start[i] = segment base (segments in arbitrary order); dinv[i] = rsqrt(deg+1).
__global__ void alloc_kernel(const int* __restrict__ cnt, int* __restrict__ row_start,
                             float* __restrict__ dinv, int* __restrict__ cursor, int n) {
    int i = blockIdx.x * blockDim.x + threadIdx.x;
    int lane = threadIdx.x & 63;
    int v = (i < n) ? cnt[i] : 0;
    int s = v;  // inclusive wave prefix
#pragma unroll
    for (int off = 1; off < 64; off <<= 1) {
        int x = __shfl_up(s, off, 64);
        if (lane >= off) s += x;
    }
    int total = __shfl(s, 63, 64);
    int base = 0;
    if (lane == 0) base = atomicAdd(cursor, total);
    base = __shfl(base, 0, 64);
    if (i < n) {
        row_start[i] = base + s - v;  // exclusive within wave
        dinv[i] = rsqrtf((float)v + 1.0f);
    }
}

// bump-fill: after completion row_start[d] == segment end (beg = end - cnt[d])
__global__ void fill_kernel(const int* __restrict__ src, const int* __restrict__ dst,
                            int* __restrict__ row_start, int* __restrict__ csr_src, int e) {
    int i = blockIdx.x * blockDim.x + threadIdx.x;
    if (i < e) {
        int d = dst[i];
        int pos = atomicAdd(&row_start[d], 1);
        csr_src[pos] = src[i];
    }
}

// ---------------- merged: LDS-tiled weight transpose-cast + input scale-cast ----------------
__global__ __launch_bounds__(256) void prep_kernel(
    const float* __restrict__ W0, const float* __restrict__ W1,
    const float* __restrict__ W2, const float* __restrict__ W3, u16* __restrict__ Wt,
    const float* __restrict__ x, const float* __restrict__ dinv,
    u16* __restrict__ Y, int N) {
    int bid = blockIdx.x;
    if (bid < 784) {
        __shared__ float tile[32][33];
        const float* W; u16* out; int K, F, kb, nb;
        if (bid < 128)      { W = W0; out = Wt;          K = 128;  F = 1024; kb = bid & 3;  nb = bid >> 2; }
        else if (bid < 640) { int l = bid - 128; W = W1; out = Wt + 131072; K = 1024; F = 512; kb = l & 31; nb = l >> 5; }
        else if (bid < 768) { int l = bid - 640; W = W2; out = Wt + 655360; K = 512;  F = 256; kb = l & 15; nb = l >> 4; }
        else                { int l = bid - 768; W = W3; out = Wt + 786432; K = 256;  F = 64;  kb = l & 7;  nb = l >> 3; }
        int k0 = kb * 32, n0 = nb * 32;
        int tx = threadIdx.x & 31, ty = threadIdx.x >> 5;
#pragma unroll
        for (int i = 0; i < 4; ++i) {
            int k = ty + i * 8;
            tile[k][tx] = W[(size_t)(k0 + k) * F + n0 + tx];  // coalesced 128B rows
        }
        __syncthreads();
#pragma unroll
        for (int i = 0; i < 4; ++i) {
            int n = ty + i * 8;
            out[(size_t)(n0 + n) * K + k0 + tx] = f2bf(tile[tx][n]);  // coalesced bf16 rows
        }
    } else {
        int gid = (bid - 784) * 256 + threadIdx.x;
        int node = gid >> 5;
        int c4 = (gid & 31) * 4;
        if (node >= N) return;
        float dv = dinv[node];
        float4 v = *reinterpret_cast<const float4*>(x + (size_t)node * 128 + c4);
        ushort4 r;
        r.x = f2bf(dv * v.x); r.y = f2bf(dv * v.y);
        r.z = f2bf(dv * v.z); r.w = f2bf(dv * v.w);
        *reinterpret_cast<ushort4*>(Y + (size_t)node * 128 + c4) = r;
    }
}

// ---------------- helpers: bf16x8 accumulate ----------------
__device__ __forceinline__ void add8(float* acc, const u16* p) {
    short8 v = *reinterpret_cast<const short8*>(p);
#pragma unroll
    for (int w = 0; w < 8; ++w) acc[w] += bf2f((u16)v[w]);
}
__device__ __forceinline__ void add8v(float* acc, short8 v) {
#pragma unroll
    for (int w = 0; w < 8; ++w) acc[w] += bf2f((u16)v[w]);
}

// generic CSR gather-accumulate with 8/4/1 unroll ladder (latency-bound gathers:
// 8 independent 16B loads in flight per lane)
__device__ __forceinline__ void gather_sum(float* acc, const u16* __restrict__ base,
                                           const int* __restrict__ csr_src,
                                           int beg, int end, int stride, int ch) {
    int e = beg;
    for (; e + 8 <= end; e += 8) {
        short8 v0 = *reinterpret_cast<const short8*>(base + (size_t)csr_src[e]     * stride + ch);
        short8 v1 = *reinterpret_cast<const short8*>(base + (size_t)csr_src[e + 1] * stride + ch);
        short8 v2 = *reinterpret_cast<const short8*>(base + (size_t)csr_src[e + 2] * stride + ch);
        short8 v3 = *reinterpret_cast<const short8*>(base + (size_t)csr_src[e + 3] * stride + ch);
        short8 v4 = *reinterpret_cast<const short8*>(base + (size_t)csr_src[e + 4] * stride + ch);
        short8 v5 = *reinterpret_cast<const short8*>(base + (size_t)csr_src[e + 5] * stride + ch);
        short8 v6 = *reinterpret_cast<const short8*>(base + (size_t)csr_src[e + 6] * stride + ch);
        short8 v7 = *reinterpret_cast<const short8*>(base + (size_t)csr_src[e + 7] * stride + ch);
        add8v(acc, v0); add8v(acc, v1); add8v(acc, v2); add8v(acc, v3);
        add8v(acc, v4); add8v(acc, v5); add8v(acc, v6); add8v(acc, v7);
    }
    for (; e + 4 <= end; e += 4) {
        short8 v0 = *reinterpret_cast<const short8*>(base + (size_t)csr_src[e]     * stride + ch);
        short8 v1 = *reinterpret_cast<const short8*>(base + (size_t)csr_src[e + 1] * stride + ch);
        short8 v2 = *reinterpret_cast<const short8*>(base + (size_t)csr_src[e + 2] * stride + ch);
        short8 v3 = *reinterpret_cast<const short8*>(base + (size_t)csr_src[e + 3] * stride + ch);
        add8v(acc, v0); add8v(acc, v1); add8v(acc, v2); add8v(acc, v3);
    }
    for (; e < end; ++e) add8(acc, base + (size_t)csr_src[e] * stride + ch);
}

// ---------------- layer-1 pre-aggregation: Z[d] = bf16(dinv[d]*(Y[d]+sum Y[src])) ----------------
__global__ void agg_pre_kernel(const int* __restrict__ row_end, const int* __restrict__ cnt,
                               const int* __restrict__ csr_src,
                               const u16* __restrict__ Y, const float* __restrict__ dinv,
                               u16* __restrict__ Z, int N) {
    int gid = blockIdx.x * blockDim.x + threadIdx.x;
    int node = gid >> 4;          // 16 threads/node
    int ch = (gid & 15) * 8;      // 8 cols each
    if (node >= N) return;
    float acc[8] = {};
    add8(acc, Y + (size_t)node * 128 + ch);  // self-loop
    int end = row_end[node], beg = end - cnt[node];
    gather_sum(acc, Y, csr_src, beg, end, 128, ch);
    float dv = dinv[node];
    short8 r;
#pragma unroll
    for (int w = 0; w < 8; ++w) r[w] = (short)f2bf(dv * acc[w]);
    *reinterpret_cast<short8*>(Z + (size_t)node * 128 + ch) = r;
}

// ---------------- MFMA bf16 GEMM (R10 form: pointer-bump staging, normal stores) -----------
// Out[N,F] from X[N,K] bf16 and Wt[F,K] bf16.
// EPI=0: Out = bf16(dinv[row] * acc)       EPI=1: Out = bf16(relu(acc + bias[col]))
// BM=128, BK=64, 256 threads = 4 waves (2x2), wave tile 64 x (BN/2).
// R11 lesson: BM=256's 128-acc tile crosses the 256-reg cliff (1 wave/SIMD, 1.8x slower).
// R12 lesson: u32-offset staging and non-temporal epilogue stores both regress.
// LDS: slot c (16B) holds global chunk (r=c>>3, q=(c^r)&7); XOR swizzle keeps
// fragment ds_read_b128 conflict-free with linear wave-uniform gl2lds dest.
template <int BN, int EPI>
__global__ __launch_bounds__(256) void gemm_mfma_kernel(
    const u16* __restrict__ X, const u16* __restrict__ Wt,
    const float* __restrict__ dinv, const float* __restrict__ bias,
    u16* __restrict__ Out, int N, int K, int F, int lgnx) {
    constexpr int BM = 128, BK = 64;
    constexpr int RA = (BM * 8) / 256;  // 4 staging rounds for A
    constexpr int RB = (BN * 8) / 256;  // 4 (BN=128) or 2 (BN=64)
    __shared__ u16 As[BM * BK];   // 16 KB
    __shared__ u16 Bs[BN * BK];   // 16 KB / 8 KB

    const int t = threadIdx.x;
    const int wave = t >> 6;
    const int lane = t & 63;
    const int m16 = lane & 15;
    const int quad = lane >> 4;

    // XCD-aware decode
    const int id = blockIdx.x;
    const int wi = id & ((8 << lgnx) - 1);
    const int g  = id >> (3 + lgnx);
    const int rb = g * 8 + (wi & 7);
    const int cb = wi >> 3;
    const int row0 = rb * BM;
    const int col0 = cb * BN;
    if (row0 >= N) return;

    constexpr int WN = BN / 2;
    constexpr int NI = 4;
    constexpr int NJ = WN / 16;
    const int wm = (wave >> 1) * 64;
    const int wn = (wave & 1) * WN;

    // ---- precompute staging pointers (global src advances by BK per iter) ----
    const u16* aSrc[RA];
    u16* aDst[RA];
#pragma unroll
    for (int rr = 0; rr < RA; ++rr) {
        int c = rr * 256 + t;
        int r = c >> 3;
        int q = (c ^ r) & 7;  // XOR swizzle
        int grow = row0 + r;
        if (grow >= N) grow = 0;  // clamped rows feed only epilogue-guarded outputs
        aSrc[rr] = X + (size_t)grow * K + q * 8;
        aDst[rr] = &As[(size_t)(rr * 256 + wave * 64) * 8];
    }
    const u16* bSrc[RB];
    u16* bDst[RB];
#pragma unroll
    for (int rr = 0; rr < RB; ++rr) {
        int c = rr * 256 + t;
        int r = c >> 3;
        int q = (c ^ r) & 7;
        bSrc[rr] = Wt + (size_t)(col0 + r) * K + q * 8;
        bDst[rr] = &Bs[(size_t)(rr * 256 + wave * 64) * 8];
    }

    // ---- fragment LDS byte offsets (u32, loop-invariant) ----
    u32 aOff[NI][2], bOff[NJ][2];
#pragma unroll
    for (int i = 0; i < NI; ++i)
#pragma unroll
        for (int h = 0; h < 2; ++h) {
            int row = wm + i * 16 + m16;
            int qg = h * 4 + quad;
            aOff[i][h] = (u32)(((row << 3) | ((qg ^ row) & 7)) * 16);
        }
#pragma unroll
    for (int j = 0; j < NJ; ++j)
#pragma unroll
        for (int h = 0; h < 2; ++h) {
            int row = wn + j * 16 + m16;
            int qg = h * 4 + quad;
            bOff[j][h] = (u32)(((row << 3) | ((qg ^ row) & 7)) * 16);
        }
    const char* AsB = reinterpret_cast<const char*>(As);
    const char* BsB = reinterpret_cast<const char*>(Bs);

    f32x4 acc[NI][NJ] = {};

    for (int k0 = 0; k0 < K; k0 += BK) {
#pragma unroll
        for (int rr = 0; rr < RA; ++rr) {
            gl2lds16(aSrc[rr], aDst[rr]);
            aSrc[rr] += BK;
        }
#pragma unroll
        for (int rr = 0; rr < RB; ++rr) {
            gl2lds16(bSrc[rr], bDst[rr]);
            bSrc[rr] += BK;
        }
        __syncthreads();  // drains vmcnt -> LDS valid

#pragma unroll
        for (int h = 0; h < 2; ++h) {  // two 16x16x32 k-slices per BK=64
            short8 af[NI], bf[NJ];
#pragma unroll
            for (int i = 0; i < NI; ++i)
                af[i] = *reinterpret_cast<const short8*>(AsB + aOff[i][h]);
#pragma unroll
            for (int j = 0; j < NJ; ++j)
                bf[j] = *reinterpret_cast<const short8*>(BsB + bOff[j][h]);
#pragma unroll
            for (int i = 0; i < NI; ++i)
#pragma unroll
                for (int j = 0; j < NJ; ++j)
                    acc[i][j] = __builtin_amdgcn_mfma_f32_16x16x32_bf16(af[i], bf[j], acc[i][j], 0, 0, 0);
        }
        __syncthreads();
    }

    // epilogue: C/D layout col=lane&15, row=quad*4+reg  [measured m89/m91]
#pragma unroll
    for (int i = 0; i < NI; ++i) {
#pragma unroll
        for (int r = 0; r < 4; ++r) {
            int grow = row0 + wm + i * 16 + quad * 4 + r;
            if (grow >= N) continue;
            float dv = (EPI == 0) ? dinv[grow] : 0.f;
#pragma unroll
            for (int j = 0; j < NJ; ++j) {
                int gcol = col0 + wn + j * 16 + m16;
                float v = acc[i][j][r];
                if (EPI == 0) v = dv * v;
                else          v = fmaxf(v + bias[gcol], 0.f);
                Out[(size_t)grow * F + gcol] = f2bf(v);
            }
        }
    }
}

// ---------------- post-aggregation: X_next = bf16(relu(dinv*(G[d]+sum G[src]) + b)) ----------------
__global__ void agg_post_kernel(const int* __restrict__ row_end, const int* __restrict__ cnt,
                                const int* __restrict__ csr_src,
                                const u16* __restrict__ Gc, const float* __restrict__ dinv,
                                const float* __restrict__ bias, u16* __restrict__ XO,
                                int N, int F, int lgG) {
    int gid = blockIdx.x * blockDim.x + threadIdx.x;
    int node = gid >> lgG;
    int ch = (gid & ((1 << lgG) - 1)) * 8;
    if (node >= N) return;
    float acc[8] = {};
    add8(acc, Gc + (size_t)node * F + ch);  // self-loop
    int end = row_end[node], beg = end - cnt[node];
    gather_sum(acc, Gc, csr_src, beg, end, F, ch);
    float dv = dinv[node];
    short8 r;
#pragma unroll
    for (int w = 0; w < 8; ++w)
        r[w] = (short)f2bf(fmaxf(fmaf(dv, acc[w], bias[ch + w]), 0.f));
    *reinterpret_cast<short8*>(XO + (size_t)node * F + ch) = r;
}

// ---------------- fused layer-4 aggregation + layer-5 dot ----------------
// x4_row = relu(dinv*(G[d]+sum G[src]) + b4)  (fp32, never materialized)
// g5[d] = dinv[d] * dot(x4_row, W5)
// 8 threads/node (F=64, 8 cols each); 8-lane shuffle reduce for the dot.
__global__ void agg_post_l5_kernel(const int* __restrict__ row_end, const int* __restrict__ cnt,
                                   const int* __restrict__ csr_src,
                                   const u16* __restrict__ Gc, const float* __restrict__ dinv,
                                   const float* __restrict__ b4, const float* __restrict__ W5,
                                   float* __restrict__ g5, int N) {
    int gid = blockIdx.x * blockDim.x + threadIdx.x;
    int node = gid >> 3;          // 8 threads/node (contiguous lanes, 64%8==0)
    int ch = (gid & 7) * 8;
    if (node >= N) return;
    float acc[8] = {};
    add8(acc, Gc + (size_t)node * 64 + ch);  // self-loop
    int end = row_end[node], beg = end - cnt[node];
    gather_sum(acc, Gc, csr_src, beg, end, 64, ch);
    float dv = dinv[node];
    float dot = 0.f;
#pragma unroll
    for (int w = 0; w < 8; ++w) {
        float v = fmaxf(fmaf(dv, acc[w], b4[ch + w]), 0.f);  // fp32 activation (no bf16 round)
        dot = fmaf(v, W5[ch + w], dot);
    }
#pragma unroll
    for (int off = 4; off > 0; off >>= 1) dot += __shfl_down(dot, off, 8);
    if ((gid & 7) == 0) g5[node] = dv * dot;
}

__global__ void agg5_kernel(const int* __restrict__ row_end, const int* __restrict__ cnt,
                            const int* __restrict__ csr_src,
                            const float* __restrict__ g5, const float* __restrict__ dinv,
                            const float* __restrict__ b5, float* __restrict__ out, int N) {
    int i = blockIdx.x * blockDim.x + threadIdx.x;
    if (i >= N) return;
    float acc = g5[i];
    int end = row_end[i], e = end - cnt[i];
    for (; e + 4 <= end; e += 4) {
        float a = g5[csr_src[e]];
        float b = g5[csr_src[e + 1]];
        float c = g5[csr_src[e + 2]];
        float d = g5[csr_src[e + 3]];
        acc += (a + b) + (c + d);
    }
    for (; e < end; ++e) acc += g5[csr_src[e]];
    out[i] = fmaxf(fmaf(dinv[i], acc, b5[0]), 0.f);
}

// ---------------- launch ----------------

static inline size_t align_up(size_t x) { return (x + 255) & ~(size_t)255; }
static inline int round_up8(int x) { return (x + 7) & ~7; }

extern "C" void kernel_launch(void* const* d_in, const int* in_sizes, int n_in,
                              void* d_out, int out_size, void* d_ws, size_t ws_size,
                              hipStream_t stream) {
    const float* x  = (const float*)d_in[0];
    const int*   ei = (const int*)d_in[1];
    const int E = in_sizes[1] / 2;
    const int N = in_sizes[0] / N_NODES_DIM0;
    const int* src = ei;
    const int* dst = ei + E;

    const float* W[5] = {(const float*)d_in[2], (const float*)d_in[4], (const float*)d_in[6],
                         (const float*)d_in[8], (const float*)d_in[10]};
    const float* B[5] = {(const float*)d_in[3], (const float*)d_in[5], (const float*)d_in[7],
                         (const float*)d_in[9], (const float*)d_in[11]};

    const int Ks[4] = {128, 1024, 512, 256};
    const int Fs[4] = {1024, 512, 256, 64};

    // workspace carve — peak ~209 MB
    char* w = (char*)d_ws;
    size_t off = 0;
    float* dinv    = (float*)(w + off); off += align_up((size_t)N * 4);
    float* g5      = (float*)(w + off); off += align_up((size_t)N * 4);
    int*   cnt     = (int*)(w + off);   off += align_up((size_t)(N + 1) * 4);  // cnt[N] = cursor
    int*   rstart  = (int*)(w + off);   off += align_up((size_t)N * 4);        // bump ptr -> row end
    int*   csr_src = (int*)(w + off);   off += align_up((size_t)E * 4);        // 1.6 MB
    // Wt: contiguous, all 4 layers (sizes are 256-multiples -> no gaps)
    u16* WtBase = (u16*)(w + off);
    u16* Wt[4];
    {
        size_t cum = 0;
        for (int l = 0; l < 4; ++l) {
            Wt[l] = WtBase + cum;
            cum += (size_t)Ks[l] * Fs[l];
        }
        off += align_up(cum * 2);
    }
    // Gc region (51.2 MB) also hosts Y+Z (12.8+12.8 MB), used only before layer-2 GEMM
    char* REG = w + off;               off += align_up((size_t)N * 512 * 2);    // 51.2 MB
    u16* Y  = (u16*)REG;
    u16* Z  = (u16*)(REG + align_up((size_t)N * 128 * 2));
    u16* Gc = (u16*)REG;
    u16* XA = (u16*)(w + off);         off += align_up((size_t)N * 1024 * 2);   // 102.4 MB
    u16* XB = (u16*)(w + off);         off += align_up((size_t)N * 512 * 2);    // 51.2 MB
    (void)ws_size;

    // ---- CSR build (scan-free) ----
    zero_int_kernel<<<(N + 1 + 255) / 256, 256, 0, stream>>>(cnt, N + 1);
    hist_kernel<<<(E + 255) / 256, 256, 0, stream>>>(dst, cnt, E);
    alloc_kernel<<<(N + 255) / 256, 256, 0, stream>>>(cnt, rstart, dinv, &cnt[N], N);
    fill_kernel<<<(E + 255) / 256, 256, 0, stream>>>(src, dst, rstart, csr_src, E);
    // after fill: rstart[i] == segment end; beg = rstart[i] - cnt[i]

    // ---- weights transpose-cast + input scale-cast, single merged launch ----
    {
        int scale_blocks = (N * 32 + 255) / 256;
        prep_kernel<<<784 + scale_blocks, 256, 0, stream>>>(
            W[0], W[1], W[2], W[3], WtBase, x, dinv, Y, N);
    }

    const int ny = (N + 127) / 128;
    const int ny8 = round_up8(ny);

    // ---- layer 1: aggregate-first (K=128 < F=1024) ----
    agg_pre_kernel<<<(N * 16 + 255) / 256, 256, 0, stream>>>(rstart, cnt, csr_src, Y, dinv, Z, N);
    {
        // F=1024, BN=128 -> nx=8, lgnx=3
        gemm_mfma_kernel<128, 1><<<ny8 * 8, 256, 0, stream>>>(Z, Wt[0], dinv, B[0], XA,
                                                              N, 128, 1024, 3);
    }

    // ---- layers 2..4: GEMM (dinv epilogue) -> aggregate; layer-4 agg fuses layer-5 dot ----
    u16* Xin[3]  = {XA, XB, XA};
    u16* Xout[3] = {XB, XA, nullptr};
    for (int l = 1; l < 4; ++l) {
        const int K = Ks[l], F = Fs[l];
        if (F >= 128) {
            int nx = F / 128;
            int lgnx = (nx == 4) ? 2 : (nx == 2) ? 1 : 0;
            gemm_mfma_kernel<128, 0><<<ny8 * nx, 256, 0, stream>>>(
                Xin[l - 1], Wt[l], dinv, B[l], Gc, N, K, F, lgnx);
        } else {
            // F=64, BN=64 -> nx=1, lgnx=0
            gemm_mfma_kernel<64, 0><<<ny8, 256, 0, stream>>>(
                Xin[l - 1], Wt[l], dinv, B[l], Gc, N, K, F, 0);
        }
        if (l < 3) {
            int lgG = (F == 512) ? 6 : 5;  // F/8 threads per node
            long long tot = (long long)N << lgG;
            agg_post_kernel<<<(unsigned)((tot + 255) / 256), 256, 0, stream>>>(
                rstart, cnt, csr_src, Gc, dinv, B[l], Xout[l - 1], N, F, lgG);
        } else {
            // fused layer-4 aggregation + layer-5 dot: writes g5 directly, no x4 buffer
            long long tot = (long long)N << 3;
            agg_post_l5_kernel<<<(unsigned)((tot + 255) / 256), 256, 0, stream>>>(
                rstart, cnt, csr_src, Gc, dinv, B[3], W[4], g5, N);
        }
    }

    // ---- layer 5 aggregation: out = relu(dinv*(g5[d]+sum g5[src]) + b5) ----
    agg5_kernel<<<(N + 255) / 256, 256, 0, stream>>>(rstart, cnt, csr_src, g5, dinv, B[4],
                                                     (float*)d_out, N);
}

// Round 15
// 415.900 us; speedup vs baseline: 1.0978x; 1.0548x over previous
//
#include <hip/hip_runtime.h>
#include <hip/hip_bf16.h>

#define N_NODES_DIM0 128

typedef unsigned short u16;
typedef unsigned int u32;
typedef __attribute__((ext_vector_type(8))) short short8;
typedef __attribute__((ext_vector_type(4))) float f32x4;

__device__ __forceinline__ float bf2f(u16 h) { return __uint_as_float((u32)h << 16); }
__device__ __forceinline__ u16 f2bf(float f) {
    u32 u = __float_as_uint(f);
    u32 r = (u + 0x7FFFu + ((u >> 16) & 1u)) >> 16;  // round-to-nearest-even
    return (u16)r;
}

// async global->LDS, 16 B per lane; lds dest = wave-uniform base + lane*16
__device__ __forceinline__ void gl2lds16(const u16* g, u16* lds_base) {
    __builtin_amdgcn_global_load_lds(
        (const __attribute__((address_space(1))) u32*)g,
        (__attribute__((address_space(3))) u32*)lds_base, 16, 0, 0);
}

// ---------------- CSR build (scan-free: wave-scan + atomic bump allocator) ----------------

__global__ void zero_int_kernel(int* p, int n) {
    int i = blockIdx.x * blockDim.x + threadIdx.x;
    if (i < n) p[i] = 0;
}

__global__ void hist_kernel(const int* __restrict__ dst, int* __restrict__ cnt, int e) {
    int i = blockIdx.x * blockDim.x + threadIdx.x;
    if (i < e) atomicAdd(&cnt[dst[i]], 1);
}

// row_start[i] = segment base (segments in arbitrary order); dinv[i] = rsqrt(deg+1).
__global__ void alloc_kernel(const int* __restrict__ cnt, int* __restrict__ row_start,
                             float* __restrict__ dinv, int* __restrict__ cursor, int n) {
    int i = blockIdx.x * blockDim.x + threadIdx.x;
    int lane = threadIdx.x & 63;
    int v = (i < n) ? cnt[i] : 0;
    int s = v;  // inclusive wave prefix
#pragma unroll
    for (int off = 1; off < 64; off <<= 1) {
        int x = __shfl_up(s, off, 64);
        if (lane >= off) s += x;
    }
    int total = __shfl(s, 63, 64);
    int base = 0;
    if (lane == 0) base = atomicAdd(cursor, total);
    base = __shfl(base, 0, 64);
    if (i < n) {
        row_start[i] = base + s - v;  // exclusive within wave
        dinv[i] = rsqrtf((float)v + 1.0f);
    }
}

// bump-fill: after completion row_start[d] == segment end (beg = end - cnt[d])
__global__ void fill_kernel(const int* __restrict__ src, const int* __restrict__ dst,
                            int* __restrict__ row_start, int* __restrict__ csr_src, int e) {
    int i = blockIdx.x * blockDim.x + threadIdx.x;
    if (i < e) {
        int d = dst[i];
        int pos = atomicAdd(&row_start[d], 1);
        csr_src[pos] = src[i];
    }
}

// ---------------- merged: LDS-tiled weight transpose-cast + input scale-cast ----------------
__global__ __launch_bounds__(256) void prep_kernel(
    const float* __restrict__ W0, const float* __restrict__ W1,
    const float* __restrict__ W2, const float* __restrict__ W3, u16* __restrict__ Wt,
    const float* __restrict__ x, const float* __restrict__ dinv,
    u16* __restrict__ Y, int N) {
    int bid = blockIdx.x;
    if (bid < 784) {
        __shared__ float tile[32][33];
        const float* W; u16* out; int K, F, kb, nb;
        if (bid < 128)      { W = W0; out = Wt;          K = 128;  F = 1024; kb = bid & 3;  nb = bid >> 2; }
        else if (bid < 640) { int l = bid - 128; W = W1; out = Wt + 131072; K = 1024; F = 512; kb = l & 31; nb = l >> 5; }
        else if (bid < 768) { int l = bid - 640; W = W2; out = Wt + 655360; K = 512;  F = 256; kb = l & 15; nb = l >> 4; }
        else                { int l = bid - 768; W = W3; out = Wt + 786432; K = 256;  F = 64;  kb = l & 7;  nb = l >> 3; }
        int k0 = kb * 32, n0 = nb * 32;
        int tx = threadIdx.x & 31, ty = threadIdx.x >> 5;
#pragma unroll
        for (int i = 0; i < 4; ++i) {
            int k = ty + i * 8;
            tile[k][tx] = W[(size_t)(k0 + k) * F + n0 + tx];  // coalesced 128B rows
        }
        __syncthreads();
#pragma unroll
        for (int i = 0; i < 4; ++i) {
            int n = ty + i * 8;
            out[(size_t)(n0 + n) * K + k0 + tx] = f2bf(tile[tx][n]);  // coalesced bf16 rows
        }
    } else {
        int gid = (bid - 784) * 256 + threadIdx.x;
        int node = gid >> 5;
        int c4 = (gid & 31) * 4;
        if (node >= N) return;
        float dv = dinv[node];
        float4 v = *reinterpret_cast<const float4*>(x + (size_t)node * 128 + c4);
        ushort4 r;
        r.x = f2bf(dv * v.x); r.y = f2bf(dv * v.y);
        r.z = f2bf(dv * v.z); r.w = f2bf(dv * v.w);
        *reinterpret_cast<ushort4*>(Y + (size_t)node * 128 + c4) = r;
    }
}

// ---------------- helpers: bf16x8 accumulate ----------------
__device__ __forceinline__ void add8(float* acc, const u16* p) {
    short8 v = *reinterpret_cast<const short8*>(p);
#pragma unroll
    for (int w = 0; w < 8; ++w) acc[w] += bf2f((u16)v[w]);
}
__device__ __forceinline__ void add8v(float* acc, short8 v) {
#pragma unroll
    for (int w = 0; w < 8; ++w) acc[w] += bf2f((u16)v[w]);
}

// generic CSR gather-accumulate with 8/4/1 unroll ladder (latency-bound gathers:
// 8 independent 16B loads in flight per lane)
__device__ __forceinline__ void gather_sum(float* acc, const u16* __restrict__ base,
                                           const int* __restrict__ csr_src,
                                           int beg, int end, int stride, int ch) {
    int e = beg;
    for (; e + 8 <= end; e += 8) {
        short8 v0 = *reinterpret_cast<const short8*>(base + (size_t)csr_src[e]     * stride + ch);
        short8 v1 = *reinterpret_cast<const short8*>(base + (size_t)csr_src[e + 1] * stride + ch);
        short8 v2 = *reinterpret_cast<const short8*>(base + (size_t)csr_src[e + 2] * stride + ch);
        short8 v3 = *reinterpret_cast<const short8*>(base + (size_t)csr_src[e + 3] * stride + ch);
        short8 v4 = *reinterpret_cast<const short8*>(base + (size_t)csr_src[e + 4] * stride + ch);
        short8 v5 = *reinterpret_cast<const short8*>(base + (size_t)csr_src[e + 5] * stride + ch);
        short8 v6 = *reinterpret_cast<const short8*>(base + (size_t)csr_src[e + 6] * stride + ch);
        short8 v7 = *reinterpret_cast<const short8*>(base + (size_t)csr_src[e + 7] * stride + ch);
        add8v(acc, v0); add8v(acc, v1); add8v(acc, v2); add8v(acc, v3);
        add8v(acc, v4); add8v(acc, v5); add8v(acc, v6); add8v(acc, v7);
    }
    for (; e + 4 <= end; e += 4) {
        short8 v0 = *reinterpret_cast<const short8*>(base + (size_t)csr_src[e]     * stride + ch);
        short8 v1 = *reinterpret_cast<const short8*>(base + (size_t)csr_src[e + 1] * stride + ch);
        short8 v2 = *reinterpret_cast<const short8*>(base + (size_t)csr_src[e + 2] * stride + ch);
        short8 v3 = *reinterpret_cast<const short8*>(base + (size_t)csr_src[e + 3] * stride + ch);
        add8v(acc, v0); add8v(acc, v1); add8v(acc, v2); add8v(acc, v3);
    }
    for (; e < end; ++e) add8(acc, base + (size_t)csr_src[e] * stride + ch);
}

// ---------------- layer-1 pre-aggregation: Z[d] = bf16(dinv[d]*(Y[d]+sum Y[src])) ----------------
__global__ void agg_pre_kernel(const int* __restrict__ row_end, const int* __restrict__ cnt,
                               const int* __restrict__ csr_src,
                               const u16* __restrict__ Y, const float* __restrict__ dinv,
                               u16* __restrict__ Z, int N) {
    int gid = blockIdx.x * blockDim.x + threadIdx.x;
    int node = gid >> 4;          // 16 threads/node
    int ch = (gid & 15) * 8;      // 8 cols each
    if (node >= N) return;
    float acc[8] = {};
    add8(acc, Y + (size_t)node * 128 + ch);  // self-loop
    int end = row_end[node], beg = end - cnt[node];
    gather_sum(acc, Y, csr_src, beg, end, 128, ch);
    float dv = dinv[node];
    short8 r;
#pragma unroll
    for (int w = 0; w < 8; ++w) r[w] = (short)f2bf(dv * acc[w]);
    *reinterpret_cast<short8*>(Z + (size_t)node * 128 + ch) = r;
}

// ---------------- MFMA bf16 GEMM (generic BN/TPB; 64x64 wave tile avoids reg cliff) --------
// Out[N,F] from X[N,K] bf16 and Wt[F,K] bf16.
// EPI=0: Out = bf16(dinv[row] * acc)       EPI=1: Out = bf16(relu(acc + bias[col]))
// BM=128, BK=64. TPB=512 w/ BN=256: 8 waves in 2x4 grid, wave tile 64x64 (acc=64 regs,
// same per-wave budget as the proven BN=128 form — R11's BM=256 died on the 128-acc
// register cliff; this grows BN instead, halving A-tile re-reads: staged traffic
// L2 820->615 MB). TPB=256 w/ BN=64 kept for the F=64 layer.
// R12 lesson: pointer-bump staging + normal stores only (u32-offsets / nt-stores regress).
// LDS: slot c (16B) holds global chunk (r=c>>3, q=(c^r)&7); XOR swizzle keeps
// fragment ds_read_b128 conflict-free with linear wave-uniform gl2lds dest.
template <int BN, int TPB, int EPI>
__global__ __launch_bounds__(TPB) void gemm_mfma_kernel(
    const u16* __restrict__ X, const u16* __restrict__ Wt,
    const float* __restrict__ dinv, const float* __restrict__ bias,
    u16* __restrict__ Out, int N, int K, int F, int lgnx) {
    constexpr int BM = 128, BK = 64;
    constexpr int RA = (BM * 8) / TPB;
    constexpr int RB = (BN * 8) / TPB;
    constexpr int WAVES = TPB / 64;
    constexpr int WAVES_N = (BN >= 64) ? (BN / 64) : 1;   // 4 (BN=256) or 1 (BN=64)
    constexpr int WAVES_M = WAVES / WAVES_N;              // 2 or 4
    constexpr int WM = BM / WAVES_M;                      // 64 or 32
    constexpr int WN = BN / WAVES_N;                      // 64
    constexpr int NI = WM / 16;                           // 4 or 2
    constexpr int NJ = WN / 16;                           // 4
    __shared__ u16 As[BM * BK];   // 16 KB
    __shared__ u16 Bs[BN * BK];   // 32 KB (BN=256) or 8 KB (BN=64)

    const int t = threadIdx.x;
    const int wave = t >> 6;
    const int lane = t & 63;
    const int m16 = lane & 15;
    const int quad = lane >> 4;

    // XCD-aware decode
    const int id = blockIdx.x;
    const int wi = id & ((8 << lgnx) - 1);
    const int g  = id >> (3 + lgnx);
    const int rb = g * 8 + (wi & 7);
    const int cb = wi >> 3;
    const int row0 = rb * BM;
    const int col0 = cb * BN;
    if (row0 >= N) return;

    const int wm = (wave / WAVES_N) * WM;
    const int wn = (wave % WAVES_N) * WN;

    // ---- precompute staging pointers (global src advances by BK per iter) ----
    const u16* aSrc[RA];
    u16* aDst[RA];
#pragma unroll
    for (int rr = 0; rr < RA; ++rr) {
        int c = rr * TPB + t;
        int r = c >> 3;
        int q = (c ^ r) & 7;  // XOR swizzle
        int grow = row0 + r;
        if (grow >= N) grow = 0;  // clamped rows feed only epilogue-guarded outputs
        aSrc[rr] = X + (size_t)grow * K + q * 8;
        aDst[rr] = &As[(size_t)(rr * TPB + wave * 64) * 8];
    }
    const u16* bSrc[RB];
    u16* bDst[RB];
#pragma unroll
    for (int rr = 0; rr < RB; ++rr) {
        int c = rr * TPB + t;
        int r = c >> 3;
        int q = (c ^ r) & 7;
        bSrc[rr] = Wt + (size_t)(col0 + r) * K + q * 8;
        bDst[rr] = &Bs[(size_t)(rr * TPB + wave * 64) * 8];
    }

    // ---- fragment LDS byte offsets (u32, loop-invariant) ----
    u32 aOff[NI][2], bOff[NJ][2];
#pragma unroll
    for (int i = 0; i < NI; ++i)
#pragma unroll
        for (int h = 0; h < 2; ++h) {
            int row = wm + i * 16 + m16;
            int qg = h * 4 + quad;
            aOff[i][h] = (u32)(((row << 3) | ((qg ^ row) & 7)) * 16);
        }
#pragma unroll
    for (int j = 0; j < NJ; ++j)
#pragma unroll
        for (int h = 0; h < 2; ++h) {
            int row = wn + j * 16 + m16;
            int qg = h * 4 + quad;
            bOff[j][h] = (u32)(((row << 3) | ((qg ^ row) & 7)) * 16);
        }
    const char* AsB = reinterpret_cast<const char*>(As);
    const char* BsB = reinterpret_cast<const char*>(Bs);

    f32x4 acc[NI][NJ] = {};

    for (int k0 = 0; k0 < K; k0 += BK) {
#pragma unroll
        for (int rr = 0; rr < RA; ++rr) {
            gl2lds16(aSrc[rr], aDst[rr]);
            aSrc[rr] += BK;
        }
#pragma unroll
        for (int rr = 0; rr < RB; ++rr) {
            gl2lds16(bSrc[rr], bDst[rr]);
            bSrc[rr] += BK;
        }
        __syncthreads();  // drains vmcnt -> LDS valid

#pragma unroll
        for (int h = 0; h < 2; ++h) {  // two 16x16x32 k-slices per BK=64
            short8 af[NI], bf[NJ];
#pragma unroll
            for (int i = 0; i < NI; ++i)
                af[i] = *reinterpret_cast<const short8*>(AsB + aOff[i][h]);
#pragma unroll
            for (int j = 0; j < NJ; ++j)
                bf[j] = *reinterpret_cast<const short8*>(BsB + bOff[j][h]);
#pragma unroll
            for (int i = 0; i < NI; ++i)
#pragma unroll
                for (int j = 0; j < NJ; ++j)
                    acc[i][j] = __builtin_amdgcn_mfma_f32_16x16x32_bf16(af[i], bf[j], acc[i][j], 0, 0, 0);
        }
        __syncthreads();
    }

    // epilogue: C/D layout col=lane&15, row=quad*4+reg  [measured m89/m91]
#pragma unroll
    for (int i = 0; i < NI; ++i) {
#pragma unroll
        for (int r = 0; r < 4; ++r) {
            int grow = row0 + wm + i * 16 + quad * 4 + r;
            if (grow >= N) continue;
            float dv = (EPI == 0) ? dinv[grow] : 0.f;
#pragma unroll
            for (int j = 0; j < NJ; ++j) {
                int gcol = col0 + wn + j * 16 + m16;
                float v = acc[i][j][r];
                if (EPI == 0) v = dv * v;
                else          v = fmaxf(v + bias[gcol], 0.f);
                Out[(size_t)grow * F + gcol] = f2bf(v);
            }
        }
    }
}

// ---------------- post-aggregation: X_next = bf16(relu(dinv*(G[d]+sum G[src]) + b)) ----------------
__global__ void agg_post_kernel(const int* __restrict__ row_end, const int* __restrict__ cnt,
                                const int* __restrict__ csr_src,
                                const u16* __restrict__ Gc, const float* __restrict__ dinv,
                                const float* __restrict__ bias, u16* __restrict__ XO,
                                int N, int F, int lgG) {
    int gid = blockIdx.x * blockDim.x + threadIdx.x;
    int node = gid >> lgG;
    int ch = (gid & ((1 << lgG) - 1)) * 8;
    if (node >= N) return;
    float acc[8] = {};
    add8(acc, Gc + (size_t)node * F + ch);  // self-loop
    int end = row_end[node], beg = end - cnt[node];
    gather_sum(acc, Gc, csr_src, beg, end, F, ch);
    float dv = dinv[node];
    short8 r;
#pragma unroll
    for (int w = 0; w < 8; ++w)
        r[w] = (short)f2bf(fmaxf(fmaf(dv, acc[w], bias[ch + w]), 0.f));
    *reinterpret_cast<short8*>(XO + (size_t)node * F + ch) = r;
}

// ---------------- fused layer-4 aggregation + layer-5 dot ----------------
__global__ void agg_post_l5_kernel(const int* __restrict__ row_end, const int* __restrict__ cnt,
                                   const int* __restrict__ csr_src,
                                   const u16* __restrict__ Gc, const float* __restrict__ dinv,
                                   const float* __restrict__ b4, const float* __restrict__ W5,
                                   float* __restrict__ g5, int N) {
    int gid = blockIdx.x * blockDim.x + threadIdx.x;
    int node = gid >> 3;          // 8 threads/node
    int ch = (gid & 7) * 8;
    if (node >= N) return;
    float acc[8] = {};
    add8(acc, Gc + (size_t)node * 64 + ch);  // self-loop
    int end = row_end[node], beg = end - cnt[node];
    gather_sum(acc, Gc, csr_src, beg, end, 64, ch);
    float dv = dinv[node];
    float dot = 0.f;
#pragma unroll
    for (int w = 0; w < 8; ++w) {
        float v = fmaxf(fmaf(dv, acc[w], b4[ch + w]), 0.f);  // fp32 activation
        dot = fmaf(v, W5[ch + w], dot);
    }
#pragma unroll
    for (int off = 4; off > 0; off >>= 1) dot += __shfl_down(dot, off, 8);
    if ((gid & 7) == 0) g5[node] = dv * dot;
}

__global__ void agg5_kernel(const int* __restrict__ row_end, const int* __restrict__ cnt,
                            const int* __restrict__ csr_src,
                            const float* __restrict__ g5, const float* __restrict__ dinv,
                            const float* __restrict__ b5, float* __restrict__ out, int N) {
    int i = blockIdx.x * blockDim.x + threadIdx.x;
    if (i >= N) return;
    float acc = g5[i];
    int end = row_end[i], e = end - cnt[i];
    for (; e + 4 <= end; e += 4) {
        float a = g5[csr_src[e]];
        float b = g5[csr_src[e + 1]];
        float c = g5[csr_src[e + 2]];
        float d = g5[csr_src[e + 3]];
        acc += (a + b) + (c + d);
    }
    for (; e < end; ++e) acc += g5[csr_src[e]];
    out[i] = fmaxf(fmaf(dinv[i], acc, b5[0]), 0.f);
}

// ---------------- launch ----------------

static inline size_t align_up(size_t x) { return (x + 255) & ~(size_t)255; }
static inline int round_up8(int x) { return (x + 7) & ~7; }

extern "C" void kernel_launch(void* const* d_in, const int* in_sizes, int n_in,
                              void* d_out, int out_size, void* d_ws, size_t ws_size,
                              hipStream_t stream) {
    const float* x  = (const float*)d_in[0];
    const int*   ei = (const int*)d_in[1];
    const int E = in_sizes[1] / 2;
    const int N = in_sizes[0] / N_NODES_DIM0;
    const int* src = ei;
    const int* dst = ei + E;

    const float* W[5] = {(const float*)d_in[2], (const float*)d_in[4], (const float*)d_in[6],
                         (const float*)d_in[8], (const float*)d_in[10]};
    const float* B[5] = {(const float*)d_in[3], (const float*)d_in[5], (const float*)d_in[7],
                         (const float*)d_in[9], (const float*)d_in[11]};

    const int Ks[4] = {128, 1024, 512, 256};
    const int Fs[4] = {1024, 512, 256, 64};

    // workspace carve — peak ~209 MB
    char* w = (char*)d_ws;
    size_t off = 0;
    float* dinv    = (float*)(w + off); off += align_up((size_t)N * 4);
    float* g5      = (float*)(w + off); off += align_up((size_t)N * 4);
    int*   cnt     = (int*)(w + off);   off += align_up((size_t)(N + 1) * 4);  // cnt[N] = cursor
    int*   rstart  = (int*)(w + off);   off += align_up((size_t)N * 4);        // bump ptr -> row end
    int*   csr_src = (int*)(w + off);   off += align_up((size_t)E * 4);        // 1.6 MB
    u16* WtBase = (u16*)(w + off);
    u16* Wt[4];
    {
        size_t cum = 0;
        for (int l = 0; l < 4; ++l) {
            Wt[l] = WtBase + cum;
            cum += (size_t)Ks[l] * Fs[l];
        }
        off += align_up(cum * 2);
    }
    char* REG = w + off;               off += align_up((size_t)N * 512 * 2);    // 51.2 MB
    u16* Y  = (u16*)REG;
    u16* Z  = (u16*)(REG + align_up((size_t)N * 128 * 2));
    u16* Gc = (u16*)REG;
    u16* XA = (u16*)(w + off);         off += align_up((size_t)N * 1024 * 2);   // 102.4 MB
    u16* XB = (u16*)(w + off);         off += align_up((size_t)N * 512 * 2);    // 51.2 MB
    (void)ws_size;

    // ---- CSR build (scan-free) ----
    zero_int_kernel<<<(N + 1 + 255) / 256, 256, 0, stream>>>(cnt, N + 1);
    hist_kernel<<<(E + 255) / 256, 256, 0, stream>>>(dst, cnt, E);
    alloc_kernel<<<(N + 255) / 256, 256, 0, stream>>>(cnt, rstart, dinv, &cnt[N], N);
    fill_kernel<<<(E + 255) / 256, 256, 0, stream>>>(src, dst, rstart, csr_src, E);

    // ---- weights transpose-cast + input scale-cast, single merged launch ----
    {
        int scale_blocks = (N * 32 + 255) / 256;
        prep_kernel<<<784 + scale_blocks, 256, 0, stream>>>(
            W[0], W[1], W[2], W[3], WtBase, x, dinv, Y, N);
    }

    const int ny = (N + 127) / 128;
    const int ny8 = round_up8(ny);

    // ---- layer 1: aggregate-first (K=128 < F=1024) ----
    agg_pre_kernel<<<(N * 16 + 255) / 256, 256, 0, stream>>>(rstart, cnt, csr_src, Y, dinv, Z, N);
    {
        // F=1024, BN=256 -> nx=4, lgnx=2
        gemm_mfma_kernel<256, 512, 1><<<ny8 * 4, 512, 0, stream>>>(Z, Wt[0], dinv, B[0], XA,
                                                                   N, 128, 1024, 2);
    }

    // ---- layers 2..4: GEMM (dinv epilogue) -> aggregate; layer-4 agg fuses layer-5 dot ----
    u16* Xin[3]  = {XA, XB, XA};
    u16* Xout[3] = {XB, XA, nullptr};
    for (int l = 1; l < 4; ++l) {
        const int K = Ks[l], F = Fs[l];
        if (F >= 256) {
            int nx = F / 256;                  // 2 (F=512) or 1 (F=256)
            int lgnx = (nx == 2) ? 1 : 0;
            gemm_mfma_kernel<256, 512, 0><<<ny8 * nx, 512, 0, stream>>>(
                Xin[l - 1], Wt[l], dinv, B[l], Gc, N, K, F, lgnx);
        } else {
            // F=64, BN=64 -> nx=1, lgnx=0
            gemm_mfma_kernel<64, 256, 0><<<ny8, 256, 0, stream>>>(
                Xin[l - 1], Wt[l], dinv, B[l], Gc, N, K, F, 0);
        }
        if (l < 3) {
            int lgG = (F == 512) ? 6 : 5;  // F/8 threads per node
            long long tot = (long long)N << lgG;
            agg_post_kernel<<<(unsigned)((tot + 255) / 256), 256, 0, stream>>>(
                rstart, cnt, csr_src, Gc, dinv, B[l], Xout[l - 1], N, F, lgG);
        } else {
            long long tot = (long long)N << 3;
            agg_post_l5_kernel<<<(unsigned)((tot + 255) / 256), 256, 0, stream>>>(
                rstart, cnt, csr_src, Gc, dinv, B[3], W[4], g5, N);
        }
    }

    // ---- layer 5 aggregation: out = relu(dinv*(g5[d]+sum g5[src]) + b5) ----
    agg5_kernel<<<(N + 255) / 256, 256, 0, stream>>>(rstart, cnt, csr_src, g5, dinv, B[4],
                                                     (float*)d_out, N);
}